// Round 7
// baseline (112.931 us; speedup 1.0000x reference)
//
#include <hip/hip_runtime.h>
#include <stdint.h>
#include <math.h>

// Problem constants
#define NV 32      // num_vari (groups)
#define NB 4096    // batch
#define NK 256     // 2*dim_per_vari (contraction)
#define NO 256     // dim_to (output features)

#define TROWS 64   // rows per m-tile
#define NTILE 4    // m-tiles per block (slab = 256 rows)

typedef __bf16 bf16x8 __attribute__((ext_vector_type(8)));
typedef __bf16 bf16x4 __attribute__((ext_vector_type(4)));
typedef float  f32x4  __attribute__((ext_vector_type(4)));

__device__ __forceinline__ f32x4 mfma16(bf16x8 a, bf16x8 b, f32x4 c) {
    return __builtin_amdgcn_mfma_f32_16x16x32_bf16(a, b, c, 0, 0, 0);
}

__device__ __forceinline__ float softplus_f(float z) {
    return fmaxf(z, 0.0f) + __logf(1.0f + __expf(-fabsf(z)));
}

// ---------------------------------------------------------------------------
// prep: W[v][k][o] fp32  ->  Wt[v][o][k] bf16  (transpose + convert, 4 MB)
__global__ __launch_bounds__(256)
void prep_wt_kernel(const float* __restrict__ w, __bf16* __restrict__ wt) {
    const int id = blockIdx.x * 256 + threadIdx.x;   // 262144
    const int o  = id & 255;
    const int kc = (id >> 8) & 31;
    const int v  = id >> 13;
    const float* src = w + ((size_t)v * NK + (size_t)kc * 8) * NO + o;
    bf16x8 r;
#pragma unroll
    for (int j = 0; j < 8; ++j) r[j] = (__bf16)src[(size_t)j * NO];
    *(bf16x8*)(wt + ((size_t)v * NO + o) * NK + kc * 8) = r;
}

// ---------------------------------------------------------------------------
// main: out[v][b][o] = softplus( x[v][b][:] . Wt[v][o][:] + 256*bias[v][o] )
//
// Per block: slab of 256 rows, 4 tiles of 64 rows. Each tile: x staged
// global->reg (full-row coalesced) -> cvt ONCE -> bf16 LDS tile (chunk-XOR
// swizzle), double-buffered, ONE barrier per tile. W streamed per tile from
// L2 (16B frags). Loads for tile tt+2 issued before the barrier (T14 split).
__global__ __launch_bounds__(512, 4)
void mv_dense_kernel(const float* __restrict__ x, const __bf16* __restrict__ wt,
                     const float* __restrict__ bias, float* __restrict__ out) {
    // bf16 tile [64 rows][256 k], row = 512 B = 32 16B-chunks.
    // phys chunk = logical chunk ^ (row & 7)  -> b128 frag reads uniform
    __shared__ __bf16 Xs[2][TROWS * NK];   // 2 x 32 KB

    const int t    = threadIdx.x;
    const int w    = t >> 6;      // wave 0..7 -> o-columns [w*32, w*32+32)
    const int lane = t & 63;
    const int lr   = lane & 15;
    const int lg   = lane >> 4;

    // XCD-chunked: 512 blocks = 8 XCD x 64; each XCD owns 4 v's (Wt 512KB/L2)
    const int bid  = blockIdx.x;
    const int lb   = (bid & 7) * 64 + (bid >> 3);
    const int v    = lb >> 4;     // 0..31
    const int slab = lb & 15;     // 0..15 -> 256 rows each

    const float* xg = x   + ((size_t)v * NB + (size_t)slab * 256) * NK;
    float*       og = out + ((size_t)v * NB + (size_t)slab * 256) * NO;

    // W fragment pointers (L2-resident bf16; re-streamed each tile)
    const __bf16* wp0 = wt + ((size_t)v * NO + w * 32 + lr) * NK + lg * 8;
    const __bf16* wp1 = wp0 + (size_t)16 * NK;

    // bias, pre-scaled by 256, laid out per C-fragment (o = w*32+j*16+lg*4+r)
    const float* bg = bias + (size_t)v * NO + w * 32 + lg * 4;
    f32x4 bb0 = *(const f32x4*)bg;
    f32x4 bb1 = *(const f32x4*)(bg + 16);
#pragma unroll
    for (int r = 0; r < 4; ++r) { bb0[r] *= 256.0f; bb1[r] *= 256.0f; }

    // staging: load instr n covers fp32 row (n*8 + w) fully: 64 lanes x 16 B
    const float* xsrc = xg + w * NK + lane * 4;
    // LDS write: row r = n*8+w; chunk = lane>>1 (b64 halves), phys = chunk ^ w
    const int ldso = w * NK + (((lane >> 1) ^ w) * 8) + (lane & 1) * 4;

    f32x4 xa[8];
    auto stage_load = [&](int tile) {
#pragma unroll
        for (int n = 0; n < 8; ++n)
            xa[n] = *(const f32x4*)(xsrc + (size_t)tile * TROWS * NK + n * 8 * NK);
    };
    auto cvt_write = [&](__bf16* buf) {
#pragma unroll
        for (int n = 0; n < 8; ++n) {
            bf16x4 hv;
#pragma unroll
            for (int e = 0; e < 4; ++e) hv[e] = (__bf16)xa[n][e];
            *(bf16x4*)&buf[n * 8 * NK + ldso] = hv;   // ds_write_b64
        }
    };

    auto compute = [&](int tile, const __bf16* buf) {
        f32x4 acc[4][2];
#pragma unroll
        for (int i = 0; i < 4; ++i)
#pragma unroll
            for (int j = 0; j < 2; ++j) {
                f32x4 z4 = {0.f, 0.f, 0.f, 0.f};
                acc[i][j] = z4;
            }
#pragma unroll
        for (int kk = 0; kk < 8; ++kk) {
            bf16x8 wv0 = *(const bf16x8*)(wp0 + kk * 32);   // L2 stream
            bf16x8 wv1 = *(const bf16x8*)(wp1 + kk * 32);
#pragma unroll
            for (int i = 0; i < 4; ++i) {
                const int row  = i * 16 + lr;
                const int phys = (kk * 4 + lg) ^ (lr & 7);
                bf16x8 afr = *(const bf16x8*)&buf[row * NK + phys * 8];
                acc[i][0] = mfma16(wv0, afr, acc[i][0]);
                acc[i][1] = mfma16(wv1, afr, acc[i][1]);
            }
        }
        // epilogue: batch = tile*64 + i*16 + lr, o = w*32 + {0,16} + lg*4 + r
#pragma unroll
        for (int i = 0; i < 4; ++i) {
            float* o = og + (size_t)(tile * TROWS + i * 16 + lr) * NO + w * 32 + lg * 4;
            f32x4 r0, r1;
#pragma unroll
            for (int r = 0; r < 4; ++r) {
                r0[r] = softplus_f(acc[i][0][r] + bb0[r]);
                r1[r] = softplus_f(acc[i][1][r] + bb1[r]);
            }
            *(f32x4*)o        = r0;
            *(f32x4*)(o + 16) = r1;
        }
    };

    // ---- prologue ----
    stage_load(0);
    asm volatile("s_waitcnt vmcnt(0)" ::: "memory");
    cvt_write(&Xs[0][0]);
    stage_load(1);
    __builtin_amdgcn_sched_barrier(0);
    __builtin_amdgcn_s_barrier();

    __bf16* cur = &Xs[0][0];
    __bf16* nxt = &Xs[1][0];
#pragma unroll 1
    for (int tt = 0; tt < NTILE; ++tt) {
        compute(tt, cur);
        if (tt + 1 < NTILE) {
            // xa(tt+1) issued before compute -> older than compute's W loads;
            // compiler waits inside compute already drained them. Hint only:
            asm volatile("s_waitcnt vmcnt(8)" ::: "memory");
            cvt_write(nxt);                      // buffer last read at tt-1 (barrier-safe)
            if (tt + 2 < NTILE) stage_load(tt + 2);
            __builtin_amdgcn_sched_barrier(0);
            __builtin_amdgcn_s_barrier();        // nxt visible; cur free next iter
            __bf16* tmp = cur; cur = nxt; nxt = tmp;
        }
    }
}

extern "C" void kernel_launch(void* const* d_in, const int* in_sizes, int n_in,
                              void* d_out, int out_size, void* d_ws, size_t ws_size,
                              hipStream_t stream) {
    const float* x  = (const float*)d_in[0];
    const float* w  = (const float*)d_in[1];
    const float* b  = (const float*)d_in[2];
    float* out      = (float*)d_out;
    __bf16* wt      = (__bf16*)d_ws;   // 4 MB scratch

    hipLaunchKernelGGL(prep_wt_kernel, dim3(1024), dim3(256), 0, stream, w, wt);
    // 512 blocks x 512 thr, 2 blocks/CU (LDS 64 KB each)
    hipLaunchKernelGGL(mv_dense_kernel, dim3(512), dim3(512), 0, stream,
                       x, wt, b, out);
}

// Round 9
// 105.214 us; speedup vs baseline: 1.0733x; 1.0733x over previous
//
#include <hip/hip_runtime.h>
#include <stdint.h>
#include <math.h>

// Problem constants
#define NV 32      // num_vari (groups)
#define NB 4096    // batch
#define NK 256     // 2*dim_per_vari (contraction)
#define NO 256     // dim_to (output features)

#define TROWS 32   // rows per m-tile
#define NTILE 8    // m-tiles per block (slab = 256 rows)

typedef __bf16 bf16x8 __attribute__((ext_vector_type(8)));
typedef float  f32x4  __attribute__((ext_vector_type(4)));

__device__ __forceinline__ f32x4 mfma16(bf16x8 a, bf16x8 b, f32x4 c) {
    return __builtin_amdgcn_mfma_f32_16x16x32_bf16(a, b, c, 0, 0, 0);
}

__device__ __forceinline__ float softplus_f(float z) {
    return fmaxf(z, 0.0f) + __logf(1.0f + __expf(-fabsf(z)));
}

__device__ __forceinline__ void gload_lds16(const void* g, void* l) {
    // async global->LDS DMA, 16 B/lane; LDS dest = wave-uniform base + lane*16
    __builtin_amdgcn_global_load_lds((const __attribute__((address_space(1))) uint32_t*)g,
                                     (__attribute__((address_space(3))) uint32_t*)l,
                                     16, 0, 0);
}

// ---------------------------------------------------------------------------
// prep: W[v][k][o] fp32  ->  Wt[v][o][k] bf16  (transpose + convert, 4 MB)
__global__ __launch_bounds__(256)
void prep_wt_kernel(const float* __restrict__ w, __bf16* __restrict__ wt) {
    const int id = blockIdx.x * 256 + threadIdx.x;   // 262144
    const int o  = id & 255;
    const int kc = (id >> 8) & 31;
    const int v  = id >> 13;
    const float* src = w + ((size_t)v * NK + (size_t)kc * 8) * NO + o;
    bf16x8 r;
#pragma unroll
    for (int j = 0; j < 8; ++j) r[j] = (__bf16)src[(size_t)j * NO];
    *(bf16x8*)(wt + ((size_t)v * NO + o) * NK + kc * 8) = r;
}

// ---------------------------------------------------------------------------
// main: out[v][b][o] = softplus( x[v][b][:] . Wt[v][o][:] + 256*bias[v][o] )
//
// Round-6-proven sync structure (fence+barrier+sched_barrier at iteration
// TOP, then stage, then compute) with 32-row tiles (halved W restream) and
// a 4-bit LDS chunk swizzle phys = slot ^ (row & 15).
__global__ __launch_bounds__(512, 4)
void mv_dense_kernel(const float* __restrict__ x, const __bf16* __restrict__ wt,
                     const float* __restrict__ bias, float* __restrict__ out) {
    __shared__ float Xs[2][TROWS * NK];   // 2 x 32 KB -> 2 blocks/CU

    const int t    = threadIdx.x;
    const int w    = t >> 6;      // wave 0..7 -> o-columns [w*32, w*32+32)
    const int lane = t & 63;
    const int lr   = lane & 15;
    const int lg   = lane >> 4;

    // XCD-chunked: 512 blocks = 8 XCD x 64; each XCD owns 4 v's (Wt 512KB/L2)
    const int bid  = blockIdx.x;
    const int lb   = (bid & 7) * 64 + (bid >> 3);
    const int v    = lb >> 4;     // 0..31
    const int slab = lb & 15;     // 256 rows each

    const float* xg = x   + ((size_t)v * NB + (size_t)slab * 256) * NK;
    float*       og = out + ((size_t)v * NB + (size_t)slab * 256) * NO;

    // W fragment pointers (bf16, L2-resident; streamed 2x16B per kk)
    const __bf16* wp0 = wt + ((size_t)v * NO + w * 32 + lr) * NK + lg * 8;
    const __bf16* wp1 = wp0 + (size_t)16 * NK;

    // bias, pre-scaled by 256, per C-fragment layout (o = w*32 + j*16 + lg*4 + r)
    const float* bg = bias + (size_t)v * NO + w * 32 + lg * 4;
    f32x4 bb0 = *(const f32x4*)bg;
    f32x4 bb1 = *(const f32x4*)(bg + 16);
#pragma unroll
    for (int r = 0; r < 4; ++r) { bb0[r] *= 256.0f; bb1[r] *= 256.0f; }

    // ---- DMA staging: 4 gload_lds/thread; wave w fills rows r = d*8+w ----
    // LDS phys slot = lane (linear dest, wave-uniform base + lane*16);
    // global source logical slot = lane ^ (r & 15),  r & 15 = w + 8*(d&1)
    auto stage = [&](int tile, int buf) {
        const float* tsrc = xg + (size_t)tile * TROWS * NK;
        char* lbase = (char*)&Xs[buf][0];
#pragma unroll
        for (int d = 0; d < 4; ++d) {
            const int r  = d * 8 + w;
            const int sl = lane ^ (w + 8 * (d & 1));
            gload_lds16(tsrc + (size_t)r * NK + sl * 4,
                        (void*)(lbase + (size_t)r * 1024));
        }
    };

    // ---- prologue ----
    stage(0, 0);
    asm volatile("s_waitcnt vmcnt(0)" ::: "memory");
    __builtin_amdgcn_s_barrier();
    __builtin_amdgcn_sched_barrier(0);
    stage(1, 1);
    __builtin_amdgcn_sched_barrier(0);

#pragma unroll 1
    for (int tt = 0; tt < NTILE; ++tt) {
        if (tt) {
            // fence: since last fence the wave issued [4 DMAs][16 W][4 stores]
            // -> vmcnt(4) retires the DMAs (tile tt ready), stores stay in flight
            asm volatile("s_waitcnt vmcnt(4)" ::: "memory");
            __builtin_amdgcn_s_barrier();
            __builtin_amdgcn_sched_barrier(0);
            if (tt + 1 < NTILE) stage(tt + 1, (tt + 1) & 1);  // buf of tile tt-1 (reads done pre-barrier)
            __builtin_amdgcn_sched_barrier(0);
        }

        const char* tb = (const char*)&Xs[tt & 1][0];
        f32x4 acc[2][2];
#pragma unroll
        for (int i = 0; i < 2; ++i)
#pragma unroll
            for (int j = 0; j < 2; ++j) {
                f32x4 z4 = {0.f, 0.f, 0.f, 0.f};
                acc[i][j] = z4;
            }

#pragma unroll
        for (int kk = 0; kk < 8; ++kk) {
            bf16x8 wv0 = *(const bf16x8*)(wp0 + kk * 32);   // L2 stream
            bf16x8 wv1 = *(const bf16x8*)(wp1 + kk * 32);
            bf16x8 afr[2];
#pragma unroll
            for (int i = 0; i < 2; ++i) {
                const int R     = i * 16 + lr;               // R & 15 == lr
                const int physA = (kk * 8 + lg * 2) ^ lr;    // 4-bit XOR swizzle
                const char* rb  = tb + (size_t)R * 1024;
                f32x4 lo = *(const f32x4*)(rb + physA * 16);
                f32x4 hi = *(const f32x4*)(rb + (physA ^ 1) * 16);
                bf16x8 a;
#pragma unroll
                for (int e = 0; e < 4; ++e) { a[e] = (__bf16)lo[e]; a[e + 4] = (__bf16)hi[e]; }
                afr[i] = a;
            }
#pragma unroll
            for (int i = 0; i < 2; ++i) {
                acc[i][0] = mfma16(wv0, afr[i], acc[i][0]);
                acc[i][1] = mfma16(wv1, afr[i], acc[i][1]);
            }
        }

        // epilogue before the next fence: stores are the 4 in-flight allowed ops
#pragma unroll
        for (int i = 0; i < 2; ++i) {
            float* o = og + (size_t)(tt * TROWS + i * 16 + lr) * NO + w * 32 + lg * 4;
            f32x4 r0, r1;
#pragma unroll
            for (int r = 0; r < 4; ++r) {
                r0[r] = softplus_f(acc[i][0][r] + bb0[r]);
                r1[r] = softplus_f(acc[i][1][r] + bb1[r]);
            }
            *(f32x4*)o        = r0;
            *(f32x4*)(o + 16) = r1;
        }
    }
}

extern "C" void kernel_launch(void* const* d_in, const int* in_sizes, int n_in,
                              void* d_out, int out_size, void* d_ws, size_t ws_size,
                              hipStream_t stream) {
    const float* x  = (const float*)d_in[0];
    const float* w  = (const float*)d_in[1];
    const float* b  = (const float*)d_in[2];
    float* out      = (float*)d_out;
    __bf16* wt      = (__bf16*)d_ws;   // 4 MB scratch

    hipLaunchKernelGGL(prep_wt_kernel, dim3(1024), dim3(256), 0, stream, w, wt);
    // 512 blocks x 512 thr = exactly 2 blocks/CU resident (LDS 64 KB each)
    hipLaunchKernelGGL(mv_dense_kernel, dim3(512), dim3(512), 0, stream,
                       x, wt, b, out);
}

// Round 10
// 76.919 us; speedup vs baseline: 1.4682x; 1.3679x over previous
//
#include <hip/hip_runtime.h>
#include <stdint.h>
#include <math.h>

// Problem constants
#define NV 32      // num_vari (groups)
#define NB 4096    // batch
#define NK 256     // 2*dim_per_vari (contraction)
#define NO 256     // dim_to (output features)

#define TROWS 16   // rows per m-tile
#define NTILE 8    // m-tiles per block (slab = 128 rows)

typedef __bf16 bf16x8 __attribute__((ext_vector_type(8)));
typedef float  f32x4  __attribute__((ext_vector_type(4)));

__device__ __forceinline__ f32x4 mfma16(bf16x8 a, bf16x8 b, f32x4 c) {
    return __builtin_amdgcn_mfma_f32_16x16x32_bf16(a, b, c, 0, 0, 0);
}

__device__ __forceinline__ float softplus_f(float z) {
    return fmaxf(z, 0.0f) + __logf(1.0f + __expf(-fabsf(z)));
}

__device__ __forceinline__ void gload_lds16(const void* g, void* l) {
    // async global->LDS DMA, 16 B/lane; LDS dest = wave-uniform base + lane*16
    __builtin_amdgcn_global_load_lds((const __attribute__((address_space(1))) uint32_t*)g,
                                     (__attribute__((address_space(3))) uint32_t*)l,
                                     16, 0, 0);
}

// ---------------------------------------------------------------------------
// prep: W[v][k][o] fp32  ->  Wt[v][o][k] bf16  (transpose + convert, 4 MB)
__global__ __launch_bounds__(256)
void prep_wt_kernel(const float* __restrict__ w, __bf16* __restrict__ wt) {
    const int id = blockIdx.x * 256 + threadIdx.x;   // 262144
    const int o  = id & 255;
    const int kc = (id >> 8) & 31;
    const int v  = id >> 13;
    const float* src = w + ((size_t)v * NK + (size_t)kc * 8) * NO + o;
    bf16x8 r;
#pragma unroll
    for (int j = 0; j < 8; ++j) r[j] = (__bf16)src[(size_t)j * NO];
    *(bf16x8*)(wt + ((size_t)v * NO + o) * NK + kc * 8) = r;
}

// ---------------------------------------------------------------------------
// main: out[v][b][o] = softplus( x[v][b][:] . Wt[v][o][:] + 256*bias[v][o] )
//
// Round-6-proven pipeline: 16-row fp32 tiles, TRIPLE buffer, DMA issued 2
// compute-phases ahead, vmcnt(4)+barrier+sched_barrier at iteration top.
// Round-9-proven 4-bit LDS slot swizzle (0 bank conflicts). Grid 1024 so
// 3 blocks/CU are resident (LDS 48 KB/block).
__global__ __launch_bounds__(512, 3)
void mv_dense_kernel(const float* __restrict__ x, const __bf16* __restrict__ wt,
                     const float* __restrict__ bias, float* __restrict__ out) {
    __shared__ float Xs[3][TROWS * NK];   // 3 x 16 KB

    const int t    = threadIdx.x;
    const int w    = t >> 6;      // wave 0..7 -> o-columns [w*32, w*32+32)
    const int lane = t & 63;
    const int lr   = lane & 15;
    const int lg   = lane >> 4;

    // XCD-chunked: 1024 blocks = 8 XCD x 128; each XCD owns 4 v's (Wt 1MB/L2)
    const int bid  = blockIdx.x;
    const int lb   = (bid & 7) * 128 + (bid >> 3);
    const int v    = lb >> 5;     // 0..31
    const int slab = lb & 31;     // 0..31 -> 128 rows each

    const float* xg = x   + ((size_t)v * NB + (size_t)slab * 128) * NK;
    float*       og = out + ((size_t)v * NB + (size_t)slab * 128) * NO;

    // W fragment pointers (bf16, L2-resident; streamed 2x16B per kk)
    const __bf16* wp0 = wt + ((size_t)v * NO + w * 32 + lr) * NK + lg * 8;
    const __bf16* wp1 = wp0 + (size_t)16 * NK;

    // bias, pre-scaled by 256, per C-fragment layout (o = w*32 + j*16 + lg*4 + r)
    const float* bg = bias + (size_t)v * NO + w * 32 + lg * 4;
    f32x4 bb0 = *(const f32x4*)bg;
    f32x4 bb1 = *(const f32x4*)(bg + 16);
#pragma unroll
    for (int r = 0; r < 4; ++r) { bb0[r] *= 256.0f; bb1[r] *= 256.0f; }

    // ---- DMA staging: 2 gload_lds/thread; wave w fills rows w and w+8 ----
    // LDS phys slot = lane (linear dest); global logical slot = lane ^ (r&15)
    auto stage = [&](int tile, int buf) {
        const float* tsrc = xg + (size_t)tile * TROWS * NK;
        char* lbase = (char*)&Xs[buf][0];
#pragma unroll
        for (int d = 0; d < 2; ++d) {
            const int r = d * 8 + w;                    // r & 15 == r
            gload_lds16(tsrc + (size_t)r * NK + (lane ^ r) * 4,
                        (void*)(lbase + (size_t)r * 1024));
        }
    };

    // compute one 16-row tile from buf (reads swizzled), stores after MFMA
    auto compute = [&](int tt, const char* tb) {
        f32x4 acc0 = {0.f, 0.f, 0.f, 0.f};
        f32x4 acc1 = {0.f, 0.f, 0.f, 0.f};
#pragma unroll
        for (int kk = 0; kk < 8; ++kk) {
            bf16x8 wv0 = *(const bf16x8*)(wp0 + kk * 32);   // L2 stream
            bf16x8 wv1 = *(const bf16x8*)(wp1 + kk * 32);
            // row = lr, logical slots {kk*8+lg*2, +1}, phys = ^ lr (4-bit XOR)
            const int phys = (kk * 8 + lg * 2) ^ lr;
            const char* rb = tb + (size_t)lr * 1024;
            f32x4 lo = *(const f32x4*)(rb + phys * 16);
            f32x4 hi = *(const f32x4*)(rb + (phys ^ 1) * 16);
            bf16x8 a;
#pragma unroll
            for (int e = 0; e < 4; ++e) { a[e] = (__bf16)lo[e]; a[e + 4] = (__bf16)hi[e]; }
            acc0 = mfma16(wv0, a, acc0);
            acc1 = mfma16(wv1, a, acc1);
        }
        // epilogue: batch = tt*16 + lr, o = w*32 + {0,16} + lg*4 + r
        float* o = og + (size_t)(tt * TROWS + lr) * NO + w * 32 + lg * 4;
        f32x4 r0, r1;
#pragma unroll
        for (int r = 0; r < 4; ++r) {
            r0[r] = softplus_f(acc0[r] + bb0[r]);
            r1[r] = softplus_f(acc1[r] + bb1[r]);
        }
        *(f32x4*)o        = r0;
        *(f32x4*)(o + 16) = r1;
    };

    // ---- pipeline prologue: 2 tiles in flight ----
    stage(0, 0);
    stage(1, 1);
    asm volatile("s_waitcnt vmcnt(0)" ::: "memory");
    __builtin_amdgcn_s_barrier();
    __builtin_amdgcn_sched_barrier(0);
    stage(2, 2);
    compute(0, (const char*)&Xs[0][0]);

    // steady state: per iter [2 DMA][16 W][2 stores]; at the fence the 4
    // youngest VMEM ops are 2 DMA(tt+1) + 2 stores(tt-1) -> vmcnt(4)
    // guarantees tile tt's DMAs have landed. ONE barrier per tile.
#pragma unroll 1
    for (int tt = 1; tt < NTILE; ++tt) {
        asm volatile("s_waitcnt vmcnt(4)" ::: "memory");
        __builtin_amdgcn_s_barrier();
        __builtin_amdgcn_sched_barrier(0);
        if (tt + 2 < NTILE) stage(tt + 2, (tt + 2) % 3);   // buf of tt-1 (reads done)
        compute(tt, (const char*)&Xs[tt % 3][0]);
    }
}

extern "C" void kernel_launch(void* const* d_in, const int* in_sizes, int n_in,
                              void* d_out, int out_size, void* d_ws, size_t ws_size,
                              hipStream_t stream) {
    const float* x  = (const float*)d_in[0];
    const float* w  = (const float*)d_in[1];
    const float* b  = (const float*)d_in[2];
    float* out      = (float*)d_out;
    __bf16* wt      = (__bf16*)d_ws;   // 4 MB scratch

    hipLaunchKernelGGL(prep_wt_kernel, dim3(1024), dim3(256), 0, stream, w, wt);
    // 1024 blocks x 512 thr; 3 blocks/CU resident (LDS 48 KB each)
    hipLaunchKernelGGL(mv_dense_kernel, dim3(NV * 32), dim3(512), 0, stream,
                       x, wt, b, out);
}

// Round 11
// 70.278 us; speedup vs baseline: 1.6069x; 1.0945x over previous
//
#include <hip/hip_runtime.h>
#include <stdint.h>
#include <math.h>

// Problem constants
#define NV 32      // num_vari (groups)
#define NB 4096    // batch
#define NK 256     // 2*dim_per_vari (contraction)
#define NO 256     // dim_to (output features)

#define TROWS 16   // rows per m-tile
#define NTILE 16   // m-tiles per block (slab = 256 rows)

typedef __bf16 bf16x8 __attribute__((ext_vector_type(8)));
typedef float  f32x4  __attribute__((ext_vector_type(4)));

__device__ __forceinline__ f32x4 mfma16(bf16x8 a, bf16x8 b, f32x4 c) {
    return __builtin_amdgcn_mfma_f32_16x16x32_bf16(a, b, c, 0, 0, 0);
}

__device__ __forceinline__ float softplus_f(float z) {
    return fmaxf(z, 0.0f) + __logf(1.0f + __expf(-fabsf(z)));
}

__device__ __forceinline__ void gload_lds16(const void* g, void* l) {
    // async global->LDS DMA, 16 B/lane; LDS dest = wave-uniform base + lane*16
    __builtin_amdgcn_global_load_lds((const __attribute__((address_space(1))) uint32_t*)g,
                                     (__attribute__((address_space(3))) uint32_t*)l,
                                     16, 0, 0);
}

// volatile-asm 16B load: result CANNOT be rematerialized by LLVM, so the
// 4 dest VGPRs stay live across the whole tile loop (the W-pinning trick).
__device__ __forceinline__ bf16x8 pin_load16(const __bf16* p) {
    bf16x8 r;
    asm volatile("global_load_dwordx4 %0, %1, off"
                 : "=v"(r) : "v"(p) : "memory");
    return r;
}

// ---------------------------------------------------------------------------
// prep: W[v][k][o] fp32  ->  Wt[v][o][k] bf16  (transpose + convert, 4 MB)
__global__ __launch_bounds__(256)
void prep_wt_kernel(const float* __restrict__ w, __bf16* __restrict__ wt) {
    const int id = blockIdx.x * 256 + threadIdx.x;   // 262144
    const int o  = id & 255;
    const int kc = (id >> 8) & 31;
    const int v  = id >> 13;
    const float* src = w + ((size_t)v * NK + (size_t)kc * 8) * NO + o;
    bf16x8 r;
#pragma unroll
    for (int j = 0; j < 8; ++j) r[j] = (__bf16)src[(size_t)j * NO];
    *(bf16x8*)(wt + ((size_t)v * NO + o) * NK + kc * 8) = r;
}

// ---------------------------------------------------------------------------
// main: out[v][b][o] = softplus( x[v][b][:] . Wt[v][o][:] + 256*bias[v][o] )
//
// W (32 o-cols/wave, 64 VGPR) pinned in registers via volatile-asm loads --
// steady-state loop has ZERO W traffic. x: 16-row fp32 tiles via
// global_load_lds DMA, TRIPLE buffer, stage-ahead-2, vmcnt(4)+barrier fence
// (round-6/10-proven), 4-bit XOR slot swizzle (round-9-proven, 0 conflicts).
__global__ __launch_bounds__(512, 4)
void mv_dense_kernel(const float* __restrict__ x, const __bf16* __restrict__ wt,
                     const float* __restrict__ bias, float* __restrict__ out) {
    __shared__ float Xs[3][TROWS * NK];   // 3 x 16 KB

    const int t    = threadIdx.x;
    const int w    = t >> 6;      // wave 0..7 -> o-columns [w*32, w*32+32)
    const int lane = t & 63;
    const int lr   = lane & 15;
    const int lg   = lane >> 4;

    // XCD-chunked: 512 blocks = 8 XCD x 64; each XCD owns 4 v's (Wt 512KB/L2)
    const int bid  = blockIdx.x;
    const int lb   = (bid & 7) * 64 + (bid >> 3);
    const int v    = lb >> 4;     // 0..31
    const int slab = lb & 15;     // 256 rows each

    const float* xg = x   + ((size_t)v * NB + (size_t)slab * 256) * NK;
    float*       og = out + ((size_t)v * NB + (size_t)slab * 256) * NO;

    // ---- pin W fragments in registers (64 VGPR, loaded once, L2-hot) ----
    const __bf16* wp0 = wt + ((size_t)v * NO + w * 32 + lr) * NK + lg * 8;
    const __bf16* wp1 = wp0 + (size_t)16 * NK;
    bf16x8 wv0[8], wv1[8];
#pragma unroll
    for (int kk = 0; kk < 8; ++kk) {
        wv0[kk] = pin_load16(wp0 + kk * 32);
        wv1[kk] = pin_load16(wp1 + kk * 32);
    }

    // bias, pre-scaled by 256, per C-fragment layout (o = w*32 + j*16 + lg*4 + r)
    const float* bg = bias + (size_t)v * NO + w * 32 + lg * 4;
    f32x4 bb0 = *(const f32x4*)bg;
    f32x4 bb1 = *(const f32x4*)(bg + 16);
#pragma unroll
    for (int r = 0; r < 4; ++r) { bb0[r] *= 256.0f; bb1[r] *= 256.0f; }

    // ---- DMA staging: 2 gload_lds/thread; wave w fills rows w and w+8 ----
    // LDS phys slot = lane (linear dest); global logical slot = lane ^ (r&15)
    auto stage = [&](int tile, int buf) {
        const float* tsrc = xg + (size_t)tile * TROWS * NK;
        char* lbase = (char*)&Xs[buf][0];
#pragma unroll
        for (int d = 0; d < 2; ++d) {
            const int r = d * 8 + w;                    // r & 15 == r
            gload_lds16(tsrc + (size_t)r * NK + (lane ^ r) * 4,
                        (void*)(lbase + (size_t)r * 1024));
        }
    };

    // compute one 16-row tile from buf; W comes from pinned registers only
    auto compute = [&](int tt, const char* tb) {
        f32x4 acc0 = {0.f, 0.f, 0.f, 0.f};
        f32x4 acc1 = {0.f, 0.f, 0.f, 0.f};
#pragma unroll
        for (int kk = 0; kk < 8; ++kk) {
            // row = lr, logical slots {kk*8+lg*2, +1}, phys = ^ lr (4-bit XOR)
            const int phys = (kk * 8 + lg * 2) ^ lr;
            const char* rb = tb + (size_t)lr * 1024;
            f32x4 lo = *(const f32x4*)(rb + phys * 16);
            f32x4 hi = *(const f32x4*)(rb + (phys ^ 1) * 16);
            bf16x8 a;
#pragma unroll
            for (int e = 0; e < 4; ++e) { a[e] = (__bf16)lo[e]; a[e + 4] = (__bf16)hi[e]; }
            acc0 = mfma16(wv0[kk], a, acc0);
            acc1 = mfma16(wv1[kk], a, acc1);
        }
        // epilogue: batch = tt*16 + lr, o = w*32 + {0,16} + lg*4 + r
        float* o = og + (size_t)(tt * TROWS + lr) * NO + w * 32 + lg * 4;
        f32x4 r0, r1;
#pragma unroll
        for (int r = 0; r < 4; ++r) {
            r0[r] = softplus_f(acc0[r] + bb0[r]);
            r1[r] = softplus_f(acc1[r] + bb1[r]);
        }
        *(f32x4*)o        = r0;
        *(f32x4*)(o + 16) = r1;
    };

    // ---- pipeline prologue: W + 2 tiles drained once ----
    stage(0, 0);
    stage(1, 1);
    asm volatile("s_waitcnt vmcnt(0)" ::: "memory");
    __builtin_amdgcn_s_barrier();
    __builtin_amdgcn_sched_barrier(0);
    stage(2, 2);
    compute(0, (const char*)&Xs[0][0]);

    // steady state: per iter [2 DMA][2 stores]; at the fence the 4 youngest
    // VMEM ops are 2 DMA(tt+1) + 2 stores(tt-1) -> vmcnt(4) guarantees tile
    // tt's DMAs landed. ONE barrier per tile; no W traffic at all.
#pragma unroll 1
    for (int tt = 1; tt < NTILE; ++tt) {
        asm volatile("s_waitcnt vmcnt(4)" ::: "memory");
        __builtin_amdgcn_s_barrier();
        __builtin_amdgcn_sched_barrier(0);
        if (tt + 2 < NTILE) stage(tt + 2, (tt + 2) % 3);   // buf of tt-1 (reads done)
        compute(tt, (const char*)&Xs[tt % 3][0]);
    }
}

extern "C" void kernel_launch(void* const* d_in, const int* in_sizes, int n_in,
                              void* d_out, int out_size, void* d_ws, size_t ws_size,
                              hipStream_t stream) {
    const float* x  = (const float*)d_in[0];
    const float* w  = (const float*)d_in[1];
    const float* b  = (const float*)d_in[2];
    float* out      = (float*)d_out;
    __bf16* wt      = (__bf16*)d_ws;   // 4 MB scratch

    hipLaunchKernelGGL(prep_wt_kernel, dim3(1024), dim3(256), 0, stream, w, wt);
    // 512 blocks x 512 thr; 2 blocks/CU resident (LDS 48 KB, VGPR <= 128)
    hipLaunchKernelGGL(mv_dense_kernel, dim3(512), dim3(512), 0, stream,
                       x, wt, b, out);
}